// Round 8
// baseline (297.999 us; speedup 1.0000x reference)
//
#include <hip/hip_runtime.h>

typedef __bf16 bf16;
typedef __attribute__((ext_vector_type(8))) __bf16 bf16x8;
typedef __attribute__((ext_vector_type(4))) float f32x4;

// async global->LDS, 16B per lane. LDS dest must be wave-uniform base; HW writes
// base + lane*16. Swizzled layouts are achieved by pre-swizzling the global src.
__device__ __forceinline__ void gload_lds16(const void* g, void* l) {
  __builtin_amdgcn_global_load_lds(
      (const __attribute__((address_space(1))) unsigned int*)(g),
      (__attribute__((address_space(3))) unsigned int*)(l),
      16, 0, 0);
}

__device__ __forceinline__ float exp2_hw(float x) {  // v_exp_f32 = 2^x, pure VALU asm
  float r; asm("v_exp_f32 %0, %1" : "=v"(r) : "v"(x)); return r;
}
__device__ __forceinline__ unsigned cvtpk_bf16(float a, float b) {  // lo=a, hi=b
  unsigned r; asm("v_cvt_pk_bf16_f32 %0, %1, %2" : "=v"(r) : "v"(a), "v"(b)); return r;
}

#define QSCALE 0.1803368867f   // 0.125 * log2(e), folded into W_Q/b_Q at pack time

// ---------------- fused pack kernel ----------------
// grid = 4876: [0,4096) pack_x | [4096,4864) pack_w | [4864,4876) pack_bias
// (pack_wo runs separately AFTER gemm1: its output aliases Wqkv.)
__global__ __launch_bounds__(256) void pack_all(const float* __restrict__ x,
                                                const float* __restrict__ WQ, const float* __restrict__ WK,
                                                const float* __restrict__ WV,
                                                const float* __restrict__ bQ, const float* __restrict__ bK,
                                                const float* __restrict__ bV,
                                                bf16* __restrict__ Xb, bf16* __restrict__ Wt,
                                                float* __restrict__ biaso) {
  __shared__ float tile[64][65];
  int bid = blockIdx.x;
  int t = threadIdx.x;
  if (bid < 4096) {                    // resid fp32 -> bf16, 8/thread
    int i = (bid * 256 + t) * 8;
    float4 a = *(const float4*)(x + i);
    float4 b = *(const float4*)(x + i + 4);
    bf16x8 v;
    v[0] = (bf16)a.x; v[1] = (bf16)a.y; v[2] = (bf16)a.z; v[3] = (bf16)a.w;
    v[4] = (bf16)b.x; v[5] = (bf16)b.y; v[6] = (bf16)b.z; v[7] = (bf16)b.w;
    *(bf16x8*)(Xb + i) = v;
  } else if (bid < 4864) {             // W_{Q,K,V}[h][k][d] -> Wt[p*1024+h*64+d][k], W_Q pre-scaled
    int wb = bid - 4096;               // 768 = 3 * 16h * 16k-tiles
    int p = wb >> 8, h = (wb >> 4) & 15, k0 = (wb & 15) * 64;
    const float* src = (p == 0 ? WQ : p == 1 ? WK : WV) + h * 65536;
    float scl = (p == 0) ? QSCALE : 1.0f;
    int c = t & 63, r4 = t >> 6;
#pragma unroll
    for (int rr = 0; rr < 16; ++rr) {
      int k = r4 + rr * 4;
      tile[k][c] = src[(k0 + k) * 64 + c];   // coalesced read along d
    }
    __syncthreads();
#pragma unroll
    for (int rr = 0; rr < 16; ++rr) {
      int d = r4 + rr * 4;
      Wt[(p * 1024 + h * 64 + d) * 1024 + k0 + c] = (bf16)(tile[c][d] * scl);
    }
  } else {                             // bias concat (b_Q pre-scaled)
    int i = (bid - 4864) * 256 + t;
    if (i < 3072) {
      int p = i >> 10, j = i & 1023;
      float v = (p == 0 ? bQ : p == 1 ? bK : bV)[j];
      biaso[i] = (p == 0) ? v * QSCALE : v;
    }
  }
}

// W_O viewed as [hd=1024][m=1024] -> Wo_t[m][hd]  (runs after gemm1; aliases Wqkv)
__global__ __launch_bounds__(256) void pack_wo(const float* __restrict__ WO, bf16* __restrict__ Wt) {
  int bid = blockIdx.x;                 // 256 = 16 hd-tiles * 16 m-tiles
  int r0 = (bid >> 4) * 64, c0 = (bid & 15) * 64;
  __shared__ float tile[64][65];
  int t = threadIdx.x, c = t & 63, r4 = t >> 6;
#pragma unroll
  for (int rr = 0; rr < 16; ++rr) {
    int r = r4 + rr * 4;
    tile[r][c] = WO[(r0 + r) * 1024 + c0 + c];
  }
  __syncthreads();
#pragma unroll
  for (int rr = 0; rr < 16; ++rr) {
    int m = r4 + rr * 4;
    Wt[(c0 + m) * 1024 + r0 + c] = (bf16)tile[c][m];
  }
}

// ---------------- GEMM: C[M,N] = A[M,K] * Bt[N,K]^T + bias ----------------
// BM=256, BN=128, BK=64; 512 threads = 8 waves (4M x 2N), per-wave 64x64 (4x4 frags).
// Bigger M-tile cuts staged-operand traffic 25% vs 128^2 (staging-BW-bound at K=1024).
// LDS rows 128B = 8 slots; XOR swizzle slot^=(row&7) via pre-swizzled global src.
template <int OUTF32>
__global__ __launch_bounds__(512, 2) void gemm_bt(const bf16* __restrict__ A, const bf16* __restrict__ Bt,
                                                  const float* __restrict__ bias, void* __restrict__ Cv,
                                                  int M, int N, int K) {
  __shared__ bf16 As[256 * 64];   // 32 KB
  __shared__ bf16 Bs[128 * 64];   // 16 KB
  int tid = threadIdx.x;
  int wv = tid >> 6, ln = tid & 63, lr = ln & 15, lh = ln >> 4;
  int wr = wv >> 1, wc = wv & 1;  // 4M x 2N wave grid
  int row0 = blockIdx.y * 256, col0 = blockIdx.x * 128;
  int ss = (ln & 7) ^ (ln >> 3);  // swizzled source slot
  const char* ga = (const char*)(A + (long)(row0 + wv * 32 + (ln >> 3)) * K) + ss * 16;
  const char* gb = (const char*)(Bt + (long)(col0 + wv * 16 + (ln >> 3)) * K) + ss * 16;
  long rowskip = (long)8 * K * 2;
  f32x4 acc[4][4] = {};
  for (int k0 = 0; k0 < K; k0 += 64) {
    // A: 8 waves x 32 rows (4 x 8-row issues); B: 8 waves x 16 rows (2 issues)
#pragma unroll
    for (int i = 0; i < 4; ++i)
      gload_lds16(ga + (long)k0 * 2 + i * rowskip, (char*)As + (wv * 32 + i * 8) * 128);
#pragma unroll
    for (int i = 0; i < 2; ++i)
      gload_lds16(gb + (long)k0 * 2 + i * rowskip, (char*)Bs + (wv * 16 + i * 8) * 128);
    __syncthreads();
    bf16x8 af[4][2], bfr[4][2];
#pragma unroll
    for (int mi = 0; mi < 4; ++mi)
#pragma unroll
      for (int ks = 0; ks < 2; ++ks) {
        int row = wr * 64 + mi * 16 + lr;
        int o = row * 128 + (((ks * 4 + lh) ^ (row & 7)) << 4);
        af[mi][ks] = *(const bf16x8*)((const char*)As + o);
      }
#pragma unroll
    for (int ni = 0; ni < 4; ++ni)
#pragma unroll
      for (int ks = 0; ks < 2; ++ks) {
        int row = wc * 64 + ni * 16 + lr;
        int o = row * 128 + (((ks * 4 + lh) ^ (row & 7)) << 4);
        bfr[ni][ks] = *(const bf16x8*)((const char*)Bs + o);
      }
    __builtin_amdgcn_s_setprio(1);
#pragma unroll
    for (int ks = 0; ks < 2; ++ks)
#pragma unroll
      for (int mi = 0; mi < 4; ++mi)
#pragma unroll
        for (int ni = 0; ni < 4; ++ni)
          acc[mi][ni] = __builtin_amdgcn_mfma_f32_16x16x32_bf16(af[mi][ks], bfr[ni][ks], acc[mi][ni], 0, 0, 0);
    __builtin_amdgcn_s_setprio(0);
    __syncthreads();
  }
  // C/D layout: col = lane&15, row = (lane>>4)*4 + reg
#pragma unroll
  for (int mi = 0; mi < 4; ++mi) {
    int row = row0 + wr * 64 + mi * 16 + lh * 4;
#pragma unroll
    for (int ni = 0; ni < 4; ++ni) {
      int col = col0 + wc * 64 + ni * 16 + lr;
      float bvv = bias[col];
#pragma unroll
      for (int r = 0; r < 4; ++r) {
        float v = acc[mi][ni][r] + bvv;
        if (OUTF32) ((float*)Cv)[(long)(row + r) * N + col] = v;
        else        ((bf16*)Cv)[(long)(row + r) * N + col] = (bf16)v;
      }
    }
  }
}

// ---------------- flash attention (swapped-operand, balanced 128-row pairs) ----------------
// grid = 512 = 64 bh * 8 pairs. Each block: 4 waves x 32 q-rows (128-row q-tile),
// processes TWO q-tiles sequentially: qt = pair and 15-pair -> exactly 34 kv-tile
// units per block; all 512 blocks identical, 2 blocks/CU for the whole kernel.
// S^T = mfma(A=K, B=Q): lane owns q=lr, 16 kv regs -> in-register softmax reduce.
// Q pre-scaled (log2 domain) at pack time. K direct from global (L2-resident).
// V^T in LDS double-buffered. P via per-wave swizzled LDS tile.
// PV = mfma(A=V^T, B=P^T) -> O^T, lane-local l. Defer-max (T13, THR=8 log2).
__global__ __launch_bounds__(256, 2) void flash(const bf16* __restrict__ Qkv, bf16* __restrict__ Z) {
  __shared__ bf16 Vt[2][64 * 64];        // [d][kv] V^T, swizzle f(d)=(d&7)^(d>>3)
  __shared__ unsigned char Pl[4][4096];  // per-wave P[q=32][kv=64] bf16, swizzle row&7
  const float MASKV = -144269.5041f;     // -1e5 * log2(e)
  int bid = blockIdx.x;
  int pair = bid >> 6;                         // 0..7
  int bh = (bid & 7) * 8 + ((bid >> 3) & 7);   // same-bh -> same XCD (bid%8)
  int b = bh >> 4, h = bh & 15;
  int tid = threadIdx.x;
  int wv = tid >> 6, ln = tid & 63, lr = ln & 15, lh = ln >> 4;
  const bf16* Qg = Qkv + (long)b * 2048 * 3072 + h * 64;
  const bf16* Kg = Qg + 1024;
  const bf16* Vg = Qg + 2048;
  int vs0 = (tid >> 3) * 2, vd0 = (tid & 7) * 8;
  char* pw = (char*)Pl[wv];

  bf16x8 v0, v1;
  auto loadV = [&](int kvrow0) {
    v0 = *(const bf16x8*)(Vg + (long)(kvrow0 + vs0) * 3072 + vd0);
    v1 = *(const bf16x8*)(Vg + (long)(kvrow0 + vs0 + 1) * 3072 + vd0);
  };
  auto writeV = [&](bf16* vd) {
#pragma unroll
    for (int j = 0; j < 8; ++j) {
      int d = vd0 + j;
      int o = (d * 128 + vs0 * 2) ^ ((((d & 7) ^ (d >> 3)) & 7) << 4);
      unsigned int pk = (unsigned int)__builtin_bit_cast(unsigned short, (bf16)v0[j])
                      | ((unsigned int)__builtin_bit_cast(unsigned short, (bf16)v1[j]) << 16);
      *(unsigned int*)((char*)vd + o) = pk;
    }
  };

#pragma unroll 1
  for (int half = 0; half < 2; ++half) {
    int qt = half ? 15 - pair : pair;    // balanced: 34 kv-units per block
    int q0 = qt * 128;
    int nt = 2 * (qt + 1);
    // prologue: stage V tile 0, load Q frags for this q-tile
    loadV(0);
    bf16x8 bq[2][2];
#pragma unroll
    for (int mi = 0; mi < 2; ++mi)
#pragma unroll
      for (int ks = 0; ks < 2; ++ks)
        bq[mi][ks] = *(const bf16x8*)(Qg + (long)(q0 + wv * 32 + mi * 16 + lr) * 3072 + ks * 32 + lh * 8);
    writeV(Vt[0]);
    __syncthreads();

    f32x4 oa[4][2] = {};                 // oa[n2=dblk][mi]: O^T[d][q]
    float m_st[2], l_st[2];
    m_st[0] = m_st[1] = -1e30f;
    l_st[0] = l_st[1] = 0.f;

    int cur = 0;
    for (int t = 0; t < nt; ++t) {
      int kv0 = t * 64;
      bool more = (t + 1 < nt);
      // K A-frags for THIS tile, direct from global (L2-hot)
      bf16x8 kf[4][2];
#pragma unroll
      for (int n = 0; n < 4; ++n)
#pragma unroll
        for (int ks = 0; ks < 2; ++ks)
          kf[n][ks] = *(const bf16x8*)(Kg + (long)(kv0 + n * 16 + lr) * 3072 + ks * 32 + lh * 8);
      if (more) loadV(kv0 + 64);         // next tile's V, consumed ~600cy later
      // S^T = K * Q^T : D[row=kv][col=q], already in log2 domain (Q pre-scaled)
      f32x4 sc[2][4];
      __builtin_amdgcn_s_setprio(1);
#pragma unroll
      for (int mi = 0; mi < 2; ++mi)
#pragma unroll
        for (int n = 0; n < 4; ++n) {
          f32x4 zacc = {0.f, 0.f, 0.f, 0.f};
          zacc = __builtin_amdgcn_mfma_f32_16x16x32_bf16(kf[n][0], bq[mi][0], zacc, 0, 0, 0);
          zacc = __builtin_amdgcn_mfma_f32_16x16x32_bf16(kf[n][1], bq[mi][1], zacc, 0, 0, 0);
          sc[mi][n] = zacc;
        }
      __builtin_amdgcn_s_setprio(0);
      // causal mask: only the diagonal-straddling tiles need it
      if (kv0 + 63 > q0) {
#pragma unroll
        for (int mi = 0; mi < 2; ++mi) {
          int qrow = q0 + wv * 32 + mi * 16 + lr;
#pragma unroll
          for (int n = 0; n < 4; ++n) {
            int kvb = kv0 + n * 16 + lh * 4;
#pragma unroll
            for (int r = 0; r < 4; ++r)
              if (kvb + r > qrow) sc[mi][n][r] = MASKV;
          }
        }
      }
      // per-q-row softmax: in-register max over 16 regs + xor16/xor32 reduce
#pragma unroll
      for (int mi = 0; mi < 2; ++mi) {
        float mx = sc[mi][0][0];
#pragma unroll
        for (int n = 0; n < 4; ++n)
#pragma unroll
          for (int r = 0; r < 4; ++r) mx = fmaxf(mx, sc[mi][n][r]);
        mx = fmaxf(mx, __shfl_xor(mx, 16));
        mx = fmaxf(mx, __shfl_xor(mx, 32));
        // defer-max: skip rescale while growth <= 8 (P bounded by 2^8, safe)
        if (!__all(mx <= m_st[mi] + 8.0f)) {
          float mn = fmaxf(m_st[mi], mx);
          float resc = exp2_hw(m_st[mi] - mn);
          m_st[mi] = mn;
          l_st[mi] *= resc;
#pragma unroll
          for (int n2 = 0; n2 < 4; ++n2)
#pragma unroll
            for (int r = 0; r < 4; ++r) oa[n2][mi][r] *= resc;
        }
        float s = 0.f;
#pragma unroll
        for (int n = 0; n < 4; ++n)
#pragma unroll
          for (int r = 0; r < 4; ++r) {
            float p = exp2_hw(sc[mi][n][r] - m_st[mi]);
            sc[mi][n][r] = p;
            s += p;
          }
        s += __shfl_xor(s, 16);
        s += __shfl_xor(s, 32);
        l_st[mi] += s;
      }
      // P -> per-wave LDS tile P[q][kv] (packed b64 writes, swizzled), no barrier needed
#pragma unroll
      for (int mi = 0; mi < 2; ++mi) {
        int row = mi * 16 + lr;
#pragma unroll
        for (int n = 0; n < 4; ++n) {
          int addr = row * 128 + ((n * 32 + lh * 8) ^ ((row & 7) << 4));
          uint2 val = { cvtpk_bf16(sc[mi][n][0], sc[mi][n][1]),
                        cvtpk_bf16(sc[mi][n][2], sc[mi][n][3]) };
          *(uint2*)(pw + addr) = val;
        }
      }
      if (more) writeV(Vt[cur ^ 1]);     // stage next V^T into other buffer
      // P^T B-frags: col=q=lr(+mi*16), k=kv
      bf16x8 pa[2][2];
#pragma unroll
      for (int mi = 0; mi < 2; ++mi)
#pragma unroll
        for (int ks = 0; ks < 2; ++ks) {
          int row = mi * 16 + lr;
          int o = row * 128 + (((ks * 4 + lh) ^ (row & 7)) << 4);
          pa[mi][ks] = *(const bf16x8*)(pw + o);
        }
      // O^T += V^T * P^T : D[row=d][col=q]
      __builtin_amdgcn_s_setprio(1);
#pragma unroll
      for (int n2 = 0; n2 < 4; ++n2) {
        int row = n2 * 16 + lr;
        int o0 = row * 128 + ((((0 + lh) ^ (row & 7) ^ ((row >> 3) & 7)) & 7) << 4);
        int o1 = row * 128 + ((((4 + lh) ^ (row & 7) ^ ((row >> 3) & 7)) & 7) << 4);
        bf16x8 vf0 = *(const bf16x8*)((const char*)Vt[cur] + o0);
        bf16x8 vf1 = *(const bf16x8*)((const char*)Vt[cur] + o1);
#pragma unroll
        for (int mi = 0; mi < 2; ++mi) {
          oa[n2][mi] = __builtin_amdgcn_mfma_f32_16x16x32_bf16(vf0, pa[mi][0], oa[n2][mi], 0, 0, 0);
          oa[n2][mi] = __builtin_amdgcn_mfma_f32_16x16x32_bf16(vf1, pa[mi][1], oa[n2][mi], 0, 0, 0);
        }
      }
      __builtin_amdgcn_s_setprio(0);
      __syncthreads();
      cur ^= 1;
    }
    // epilogue: O = oa / l, lane-local l (q=lr). Z[(b*2048+q)*1024 + h*64 + d], 8B stores.
#pragma unroll
    for (int mi = 0; mi < 2; ++mi) {
      float inv = 1.0f / l_st[mi];
      int q = q0 + wv * 32 + mi * 16 + lr;
      bf16* zb = Z + ((long)b * 2048 + q) * 1024 + h * 64 + lh * 4;
#pragma unroll
      for (int n2 = 0; n2 < 4; ++n2) {
        uint2 o2 = { cvtpk_bf16(oa[n2][mi][0] * inv, oa[n2][mi][1] * inv),
                     cvtpk_bf16(oa[n2][mi][2] * inv, oa[n2][mi][3] * inv) };
        *(uint2*)(zb + n2 * 16) = o2;
      }
    }
    // last tile's __syncthreads guarantees Vt/Pl free for next half's prologue
  }
}

// ---------------- launch ----------------
extern "C" void kernel_launch(void* const* d_in, const int* in_sizes, int n_in,
                              void* d_out, int out_size, void* d_ws, size_t ws_size,
                              hipStream_t stream) {
  const float* resid = (const float*)d_in[0];
  const float* WQ = (const float*)d_in[1];
  const float* WK = (const float*)d_in[2];
  const float* WV = (const float*)d_in[3];
  const float* WO = (const float*)d_in[4];
  const float* bQ = (const float*)d_in[5];
  const float* bK = (const float*)d_in[6];
  const float* bV = (const float*)d_in[7];
  const float* bO = (const float*)d_in[8];
  char* ws = (char*)d_ws;
  // layout (with aliasing): [Xb|Z 16.78MB][Wqkv|Wot 6.29MB][bias 16KB][QKVo 50.33MB] = 73.4MB
  bf16*  Xb      = (bf16*)ws;
  bf16*  Z       = (bf16*)ws;                      // aliases Xb (dead after QKV GEMM)
  bf16*  Wqkv    = (bf16*)(ws + 16777216);
  bf16*  Wot     = (bf16*)(ws + 16777216);         // aliases Wqkv (dead after QKV GEMM)
  float* biasqkv = (float*)(ws + 23068672);
  bf16*  QKVo    = (bf16*)(ws + 23085056);

  pack_all<<<4876, 256, 0, stream>>>(resid, WQ, WK, WV, bQ, bK, bV, Xb, Wqkv, biasqkv);
  gemm_bt<0><<<dim3(24, 32), 512, 0, stream>>>(Xb, Wqkv, biasqkv, QKVo, 8192, 3072, 1024);
  pack_wo<<<256, 256, 0, stream>>>(WO, Wot);       // after gemm<0> has consumed Wqkv
  flash<<<512, 256, 0, stream>>>(QKVo, Z);         // writes over Xb (already consumed)
  gemm_bt<1><<<dim3(8, 32), 512, 0, stream>>>(Z, Wot, bO, d_out, 8192, 1024, 1024);
}

// Round 9
// 271.511 us; speedup vs baseline: 1.0976x; 1.0976x over previous
//
#include <hip/hip_runtime.h>

typedef __bf16 bf16;
typedef __attribute__((ext_vector_type(8))) __bf16 bf16x8;
typedef __attribute__((ext_vector_type(4))) float f32x4;

// async global->LDS, 16B per lane. LDS dest must be wave-uniform base; HW writes
// base + lane*16. Swizzled layouts are achieved by pre-swizzling the global src.
__device__ __forceinline__ void gload_lds16(const void* g, void* l) {
  __builtin_amdgcn_global_load_lds(
      (const __attribute__((address_space(1))) unsigned int*)(g),
      (__attribute__((address_space(3))) unsigned int*)(l),
      16, 0, 0);
}

__device__ __forceinline__ float exp2_hw(float x) {  // v_exp_f32 = 2^x, pure VALU asm
  float r; asm("v_exp_f32 %0, %1" : "=v"(r) : "v"(x)); return r;
}
__device__ __forceinline__ unsigned cvtpk_bf16(float a, float b) {  // lo=a, hi=b
  unsigned r; asm("v_cvt_pk_bf16_f32 %0, %1, %2" : "=v"(r) : "v"(a), "v"(b)); return r;
}

#define QSCALE 0.1803368867f   // 0.125 * log2(e), folded into W_Q/b_Q at pack time

// ---------------- fused pack kernel ----------------
// grid = 4876: [0,4096) pack_x | [4096,4864) pack_w | [4864,4876) pack_bias
// (pack_wo runs separately AFTER gemm1: its output aliases Wqkv.)
__global__ __launch_bounds__(256) void pack_all(const float* __restrict__ x,
                                                const float* __restrict__ WQ, const float* __restrict__ WK,
                                                const float* __restrict__ WV,
                                                const float* __restrict__ bQ, const float* __restrict__ bK,
                                                const float* __restrict__ bV,
                                                bf16* __restrict__ Xb, bf16* __restrict__ Wt,
                                                float* __restrict__ biaso) {
  __shared__ float tile[64][65];
  int bid = blockIdx.x;
  int t = threadIdx.x;
  if (bid < 4096) {                    // resid fp32 -> bf16, 8/thread
    int i = (bid * 256 + t) * 8;
    float4 a = *(const float4*)(x + i);
    float4 b = *(const float4*)(x + i + 4);
    bf16x8 v;
    v[0] = (bf16)a.x; v[1] = (bf16)a.y; v[2] = (bf16)a.z; v[3] = (bf16)a.w;
    v[4] = (bf16)b.x; v[5] = (bf16)b.y; v[6] = (bf16)b.z; v[7] = (bf16)b.w;
    *(bf16x8*)(Xb + i) = v;
  } else if (bid < 4864) {             // W_{Q,K,V}[h][k][d] -> Wt[p*1024+h*64+d][k], W_Q pre-scaled
    int wb = bid - 4096;               // 768 = 3 * 16h * 16k-tiles
    int p = wb >> 8, h = (wb >> 4) & 15, k0 = (wb & 15) * 64;
    const float* src = (p == 0 ? WQ : p == 1 ? WK : WV) + h * 65536;
    float scl = (p == 0) ? QSCALE : 1.0f;
    int c = t & 63, r4 = t >> 6;
#pragma unroll
    for (int rr = 0; rr < 16; ++rr) {
      int k = r4 + rr * 4;
      tile[k][c] = src[(k0 + k) * 64 + c];   // coalesced read along d
    }
    __syncthreads();
#pragma unroll
    for (int rr = 0; rr < 16; ++rr) {
      int d = r4 + rr * 4;
      Wt[(p * 1024 + h * 64 + d) * 1024 + k0 + c] = (bf16)(tile[c][d] * scl);
    }
  } else {                             // bias concat (b_Q pre-scaled)
    int i = (bid - 4864) * 256 + t;
    if (i < 3072) {
      int p = i >> 10, j = i & 1023;
      float v = (p == 0 ? bQ : p == 1 ? bK : bV)[j];
      biaso[i] = (p == 0) ? v * QSCALE : v;
    }
  }
}

// W_O viewed as [hd=1024][m=1024] -> Wo_t[m][hd]  (runs after gemm1; aliases Wqkv)
__global__ __launch_bounds__(256) void pack_wo(const float* __restrict__ WO, bf16* __restrict__ Wt) {
  int bid = blockIdx.x;                 // 256 = 16 hd-tiles * 16 m-tiles
  int r0 = (bid >> 4) * 64, c0 = (bid & 15) * 64;
  __shared__ float tile[64][65];
  int t = threadIdx.x, c = t & 63, r4 = t >> 6;
#pragma unroll
  for (int rr = 0; rr < 16; ++rr) {
    int r = r4 + rr * 4;
    tile[r][c] = WO[(r0 + r) * 1024 + c0 + c];
  }
  __syncthreads();
#pragma unroll
  for (int rr = 0; rr < 16; ++rr) {
    int m = r4 + rr * 4;
    Wt[(c0 + m) * 1024 + r0 + c] = (bf16)tile[c][m];
  }
}

// ---------------- GEMM: C[M,N] = A[M,K] * Bt[N,K]^T + bias ----------------
// R7 kernel (known-good ~860 TF at gemm1 shape): 128x128 tile, BK=64, 4 waves 2x2,
// 4x4 16x16x32 frags/wave. XOR swizzle slot^=(row&7) via pre-swizzled global src.
template <int OUTF32>
__global__ __launch_bounds__(256, 2) void gemm_bt(const bf16* __restrict__ A, const bf16* __restrict__ Bt,
                                                  const float* __restrict__ bias, void* __restrict__ Cv,
                                                  int M, int N, int K) {
  __shared__ bf16 As[128 * 64];
  __shared__ bf16 Bs[128 * 64];
  int tid = threadIdx.x;
  int wv = tid >> 6, ln = tid & 63, lr = ln & 15, lh = ln >> 4;
  int wr = wv >> 1, wc = wv & 1;
  int row0 = blockIdx.y * 128, col0 = blockIdx.x * 128;
  int ss = (ln & 7) ^ (ln >> 3);
  const char* ga = (const char*)(A + (long)(row0 + wv * 32 + (ln >> 3)) * K) + ss * 16;
  const char* gb = (const char*)(Bt + (long)(col0 + wv * 32 + (ln >> 3)) * K) + ss * 16;
  long rowskip = (long)8 * K * 2;
  f32x4 acc[4][4] = {};
  for (int k0 = 0; k0 < K; k0 += 64) {
#pragma unroll
    for (int i = 0; i < 4; ++i) {
      gload_lds16(ga + (long)k0 * 2 + i * rowskip, (char*)As + (wv * 32 + i * 8) * 128);
      gload_lds16(gb + (long)k0 * 2 + i * rowskip, (char*)Bs + (wv * 32 + i * 8) * 128);
    }
    __syncthreads();
    bf16x8 af[4][2], bfr[4][2];
#pragma unroll
    for (int mi = 0; mi < 4; ++mi)
#pragma unroll
      for (int ks = 0; ks < 2; ++ks) {
        int row = wr * 64 + mi * 16 + lr;
        int o = row * 128 + (((ks * 4 + lh) ^ (row & 7)) << 4);
        af[mi][ks] = *(const bf16x8*)((const char*)As + o);
      }
#pragma unroll
    for (int ni = 0; ni < 4; ++ni)
#pragma unroll
      for (int ks = 0; ks < 2; ++ks) {
        int row = wc * 64 + ni * 16 + lr;
        int o = row * 128 + (((ks * 4 + lh) ^ (row & 7)) << 4);
        bfr[ni][ks] = *(const bf16x8*)((const char*)Bs + o);
      }
    __builtin_amdgcn_s_setprio(1);
#pragma unroll
    for (int ks = 0; ks < 2; ++ks)
#pragma unroll
      for (int mi = 0; mi < 4; ++mi)
#pragma unroll
        for (int ni = 0; ni < 4; ++ni)
          acc[mi][ni] = __builtin_amdgcn_mfma_f32_16x16x32_bf16(af[mi][ks], bfr[ni][ks], acc[mi][ni], 0, 0, 0);
    __builtin_amdgcn_s_setprio(0);
    __syncthreads();
  }
#pragma unroll
  for (int mi = 0; mi < 4; ++mi) {
    int row = row0 + wr * 64 + mi * 16 + lh * 4;
#pragma unroll
    for (int ni = 0; ni < 4; ++ni) {
      int col = col0 + wc * 64 + ni * 16 + lr;
      float bvv = bias[col];
#pragma unroll
      for (int r = 0; r < 4; ++r) {
        float v = acc[mi][ni][r] + bvv;
        if (OUTF32) ((float*)Cv)[(long)(row + r) * N + col] = v;
        else        ((bf16*)Cv)[(long)(row + r) * N + col] = (bf16)v;
      }
    }
  }
}

// ---------------- flash attention (swapped-operand, balanced pairs, K dbuf) ----------------
// grid = 512 = 64 bh * 8 pairs; 4 waves x 32 q-rows (128-row tile); two q-tiles/block
// (qt = pair, 15-pair) -> 34 kv-units/block, all blocks identical.
// kv-loop unrolled by 2 (nt always even) with named kfA/kfB K-frag sets: K(t+1) issued
// right after QK(t)'s MFMAs, consumed after the barrier -> L2 latency hidden.
__global__ __launch_bounds__(256, 2) void flash(const bf16* __restrict__ Qkv, bf16* __restrict__ Z) {
  __shared__ bf16 Vt[2][64 * 64];        // [d][kv] V^T, swizzle f(d)=(d&7)^(d>>3)
  __shared__ unsigned char Pl[4][4096];  // per-wave P[q=32][kv=64] bf16, swizzle row&7
  const float MASKV = -144269.5041f;     // -1e5 * log2(e)
  int bid = blockIdx.x;
  int pair = bid >> 6;                         // 0..7
  int bh = (bid & 7) * 8 + ((bid >> 3) & 7);   // same-bh -> same XCD (bid%8)
  int b = bh >> 4, h = bh & 15;
  int tid = threadIdx.x;
  int wv = tid >> 6, ln = tid & 63, lr = ln & 15, lh = ln >> 4;
  const bf16* Qg = Qkv + (long)b * 2048 * 3072 + h * 64;
  const bf16* Kg = Qg + 1024;
  const bf16* Vg = Qg + 2048;
  int vs0 = (tid >> 3) * 2, vd0 = (tid & 7) * 8;
  char* pw = (char*)Pl[wv];

  bf16x8 v0, v1;
  auto loadV = [&](int kvrow0) {
    v0 = *(const bf16x8*)(Vg + (long)(kvrow0 + vs0) * 3072 + vd0);
    v1 = *(const bf16x8*)(Vg + (long)(kvrow0 + vs0 + 1) * 3072 + vd0);
  };
  auto writeV = [&](bf16* vd) {
#pragma unroll
    for (int j = 0; j < 8; ++j) {
      int d = vd0 + j;
      int o = (d * 128 + vs0 * 2) ^ ((((d & 7) ^ (d >> 3)) & 7) << 4);
      unsigned int pk = (unsigned int)__builtin_bit_cast(unsigned short, (bf16)v0[j])
                      | ((unsigned int)__builtin_bit_cast(unsigned short, (bf16)v1[j]) << 16);
      *(unsigned int*)((char*)vd + o) = pk;
    }
  };

// one kv-tile step; KF = this tile's K frags, KFN = next tile's (prefetched here)
#define FLASH_STEP(T, KF, KFN) do {                                                   \
    int kv0 = (T) * 64;                                                               \
    bool more = (T) + 1 < nt;                                                         \
    if (more) loadV(kv0 + 64);                                                        \
    f32x4 sc[2][4];                                                                   \
    __builtin_amdgcn_s_setprio(1);                                                    \
    _Pragma("unroll")                                                                 \
    for (int mi = 0; mi < 2; ++mi)                                                    \
      _Pragma("unroll")                                                               \
      for (int n = 0; n < 4; ++n) {                                                   \
        f32x4 zacc = {0.f, 0.f, 0.f, 0.f};                                            \
        zacc = __builtin_amdgcn_mfma_f32_16x16x32_bf16(KF[n][0], bq[mi][0], zacc, 0, 0, 0); \
        zacc = __builtin_amdgcn_mfma_f32_16x16x32_bf16(KF[n][1], bq[mi][1], zacc, 0, 0, 0); \
        sc[mi][n] = zacc;                                                             \
      }                                                                               \
    __builtin_amdgcn_s_setprio(0);                                                    \
    if (more) {                        /* prefetch K(T+1): consumed after barrier */  \
      _Pragma("unroll")                                                               \
      for (int n = 0; n < 4; ++n)                                                     \
        _Pragma("unroll")                                                             \
        for (int ks = 0; ks < 2; ++ks)                                                \
          KFN[n][ks] = *(const bf16x8*)(Kg + (long)(kv0 + 64 + n * 16 + lr) * 3072 + ks * 32 + lh * 8); \
    }                                                                                 \
    if (kv0 + 63 > q0) {                                                              \
      _Pragma("unroll")                                                               \
      for (int mi = 0; mi < 2; ++mi) {                                                \
        int qrow = q0 + wv * 32 + mi * 16 + lr;                                       \
        _Pragma("unroll")                                                             \
        for (int n = 0; n < 4; ++n) {                                                 \
          int kvb = kv0 + n * 16 + lh * 4;                                            \
          _Pragma("unroll")                                                           \
          for (int r = 0; r < 4; ++r)                                                 \
            if (kvb + r > qrow) sc[mi][n][r] = MASKV;                                 \
        }                                                                             \
      }                                                                               \
    }                                                                                 \
    _Pragma("unroll")                                                                 \
    for (int mi = 0; mi < 2; ++mi) {                                                  \
      float mx = sc[mi][0][0];                                                        \
      _Pragma("unroll")                                                               \
      for (int n = 0; n < 4; ++n)                                                     \
        _Pragma("unroll")                                                             \
        for (int r = 0; r < 4; ++r) mx = fmaxf(mx, sc[mi][n][r]);                     \
      mx = fmaxf(mx, __shfl_xor(mx, 16));                                             \
      mx = fmaxf(mx, __shfl_xor(mx, 32));                                             \
      if (!__all(mx <= m_st[mi] + 8.0f)) {   /* defer-max */                          \
        float mn = fmaxf(m_st[mi], mx);                                               \
        float resc = exp2_hw(m_st[mi] - mn);                                          \
        m_st[mi] = mn;                                                                \
        l_st[mi] *= resc;                                                             \
        _Pragma("unroll")                                                             \
        for (int n2 = 0; n2 < 4; ++n2)                                                \
          _Pragma("unroll")                                                           \
          for (int r = 0; r < 4; ++r) oa[n2][mi][r] *= resc;                          \
      }                                                                               \
      float s = 0.f;                                                                  \
      _Pragma("unroll")                                                               \
      for (int n = 0; n < 4; ++n)                                                     \
        _Pragma("unroll")                                                             \
        for (int r = 0; r < 4; ++r) {                                                 \
          float p = exp2_hw(sc[mi][n][r] - m_st[mi]);                                 \
          sc[mi][n][r] = p;                                                           \
          s += p;                                                                     \
        }                                                                             \
      s += __shfl_xor(s, 16);                                                         \
      s += __shfl_xor(s, 32);                                                         \
      l_st[mi] += s;                                                                  \
    }                                                                                 \
    _Pragma("unroll")                                                                 \
    for (int mi = 0; mi < 2; ++mi) {                                                  \
      int row = mi * 16 + lr;                                                         \
      _Pragma("unroll")                                                               \
      for (int n = 0; n < 4; ++n) {                                                   \
        int addr = row * 128 + ((n * 32 + lh * 8) ^ ((row & 7) << 4));                \
        uint2 val = { cvtpk_bf16(sc[mi][n][0], sc[mi][n][1]),                         \
                      cvtpk_bf16(sc[mi][n][2], sc[mi][n][3]) };                       \
        *(uint2*)(pw + addr) = val;                                                   \
      }                                                                               \
    }                                                                                 \
    if (more) writeV(Vt[cur ^ 1]);                                                    \
    bf16x8 pa[2][2];                                                                  \
    _Pragma("unroll")                                                                 \
    for (int mi = 0; mi < 2; ++mi)                                                    \
      _Pragma("unroll")                                                               \
      for (int ks = 0; ks < 2; ++ks) {                                                \
        int row = mi * 16 + lr;                                                       \
        int o = row * 128 + (((ks * 4 + lh) ^ (row & 7)) << 4);                       \
        pa[mi][ks] = *(const bf16x8*)(pw + o);                                        \
      }                                                                               \
    __builtin_amdgcn_s_setprio(1);                                                    \
    _Pragma("unroll")                                                                 \
    for (int n2 = 0; n2 < 4; ++n2) {                                                  \
      int row = n2 * 16 + lr;                                                         \
      int o0 = row * 128 + ((((0 + lh) ^ (row & 7) ^ ((row >> 3) & 7)) & 7) << 4);    \
      int o1 = row * 128 + ((((4 + lh) ^ (row & 7) ^ ((row >> 3) & 7)) & 7) << 4);    \
      bf16x8 vf0 = *(const bf16x8*)((const char*)Vt[cur] + o0);                       \
      bf16x8 vf1 = *(const bf16x8*)((const char*)Vt[cur] + o1);                       \
      _Pragma("unroll")                                                               \
      for (int mi = 0; mi < 2; ++mi) {                                                \
        oa[n2][mi] = __builtin_amdgcn_mfma_f32_16x16x32_bf16(vf0, pa[mi][0], oa[n2][mi], 0, 0, 0); \
        oa[n2][mi] = __builtin_amdgcn_mfma_f32_16x16x32_bf16(vf1, pa[mi][1], oa[n2][mi], 0, 0, 0); \
      }                                                                               \
    }                                                                                 \
    __builtin_amdgcn_s_setprio(0);                                                    \
    __syncthreads();                                                                  \
    cur ^= 1;                                                                         \
  } while (0)

#pragma unroll 1
  for (int half = 0; half < 2; ++half) {
    int qt = half ? 15 - pair : pair;    // balanced: 34 kv-units per block
    int q0 = qt * 128;
    int nt = 2 * (qt + 1);
    // prologue: stage V tile 0 + K tile 0, load Q frags
    loadV(0);
    bf16x8 bq[2][2];
#pragma unroll
    for (int mi = 0; mi < 2; ++mi)
#pragma unroll
      for (int ks = 0; ks < 2; ++ks)
        bq[mi][ks] = *(const bf16x8*)(Qg + (long)(q0 + wv * 32 + mi * 16 + lr) * 3072 + ks * 32 + lh * 8);
    bf16x8 kfA[4][2], kfB[4][2];
#pragma unroll
    for (int n = 0; n < 4; ++n)
#pragma unroll
      for (int ks = 0; ks < 2; ++ks)
        kfA[n][ks] = *(const bf16x8*)(Kg + (long)(n * 16 + lr) * 3072 + ks * 32 + lh * 8);
    writeV(Vt[0]);
    __syncthreads();

    f32x4 oa[4][2] = {};                 // oa[n2=dblk][mi]: O^T[d][q]
    float m_st[2], l_st[2];
    m_st[0] = m_st[1] = -1e30f;
    l_st[0] = l_st[1] = 0.f;

    int cur = 0;
#pragma unroll 1
    for (int t = 0; t < nt; t += 2) {    // nt always even
      FLASH_STEP(t, kfA, kfB);
      FLASH_STEP(t + 1, kfB, kfA);
    }
    // epilogue: O = oa / l, lane-local l (q=lr). Z[(b*2048+q)*1024 + h*64 + d], 8B stores.
#pragma unroll
    for (int mi = 0; mi < 2; ++mi) {
      float inv = 1.0f / l_st[mi];
      int q = q0 + wv * 32 + mi * 16 + lr;
      bf16* zb = Z + ((long)b * 2048 + q) * 1024 + h * 64 + lh * 4;
#pragma unroll
      for (int n2 = 0; n2 < 4; ++n2) {
        uint2 o2 = { cvtpk_bf16(oa[n2][mi][0] * inv, oa[n2][mi][1] * inv),
                     cvtpk_bf16(oa[n2][mi][2] * inv, oa[n2][mi][3] * inv) };
        *(uint2*)(zb + n2 * 16) = o2;
      }
    }
    // last tile's __syncthreads guarantees Vt/Pl free for next half's prologue
  }
#undef FLASH_STEP
}

// ---------------- launch ----------------
extern "C" void kernel_launch(void* const* d_in, const int* in_sizes, int n_in,
                              void* d_out, int out_size, void* d_ws, size_t ws_size,
                              hipStream_t stream) {
  const float* resid = (const float*)d_in[0];
  const float* WQ = (const float*)d_in[1];
  const float* WK = (const float*)d_in[2];
  const float* WV = (const float*)d_in[3];
  const float* WO = (const float*)d_in[4];
  const float* bQ = (const float*)d_in[5];
  const float* bK = (const float*)d_in[6];
  const float* bV = (const float*)d_in[7];
  const float* bO = (const float*)d_in[8];
  char* ws = (char*)d_ws;
  // layout (with aliasing): [Xb|Z 16.78MB][Wqkv|Wot 6.29MB][bias 16KB][QKVo 50.33MB] = 73.4MB
  bf16*  Xb      = (bf16*)ws;
  bf16*  Z       = (bf16*)ws;                      // aliases Xb (dead after QKV GEMM)
  bf16*  Wqkv    = (bf16*)(ws + 16777216);
  bf16*  Wot     = (bf16*)(ws + 16777216);         // aliases Wqkv (dead after QKV GEMM)
  float* biasqkv = (float*)(ws + 23068672);
  bf16*  QKVo    = (bf16*)(ws + 23085056);

  pack_all<<<4876, 256, 0, stream>>>(resid, WQ, WK, WV, bQ, bK, bV, Xb, Wqkv, biasqkv);
  gemm_bt<0><<<dim3(24, 64), 256, 0, stream>>>(Xb, Wqkv, biasqkv, QKVo, 8192, 3072, 1024);
  pack_wo<<<256, 256, 0, stream>>>(WO, Wot);       // after gemm<0> has consumed Wqkv
  flash<<<512, 256, 0, stream>>>(QKVo, Z);         // writes over Xb (already consumed)
  gemm_bt<1><<<dim3(8, 64), 256, 0, stream>>>(Z, Wot, bO, d_out, 8192, 1024, 1024);
}